// Round 1
// baseline (1137.368 us; speedup 1.0000x reference)
//
#include <hip/hip_runtime.h>

#define NBUCKETS 65536
#define EPS 1e-12

// ws layout:
//   [0, 256KB)       float  S[65536]   sum of exp(x) per time bucket
//   [256KB, 512KB)   uint   m[65536]   event count per time bucket
//   [512KB, +4)      float  sum_ex     sum of x over events
//   [512KB+4, +8)    uint   n_ev       total event count

__global__ void zero_ws_kernel(float* __restrict__ S, unsigned int* __restrict__ m,
                               float* __restrict__ sum_ex, unsigned int* __restrict__ n_ev) {
    int i = blockIdx.x * blockDim.x + threadIdx.x;
    if (i < NBUCKETS) { S[i] = 0.0f; m[i] = 0u; }
    if (i == 0) { *sum_ex = 0.0f; *n_ev = 0u; }
}

__global__ void scatter_kernel(const float4* __restrict__ x4, const int4* __restrict__ e4,
                               const int4* __restrict__ t4,
                               float* __restrict__ S, unsigned int* __restrict__ m,
                               float* __restrict__ sum_ex, unsigned int* __restrict__ n_ev,
                               int n4, const float* __restrict__ x_s,
                               const int* __restrict__ e_s, const int* __restrict__ t_s,
                               int tail_base, int tail_cnt) {
    int i = blockIdx.x * blockDim.x + threadIdx.x;
    float ev_x = 0.0f;
    unsigned int ev_c = 0u;
    if (i < n4) {
        float4 x = x4[i];
        int4 e = e4[i];
        int4 t = t4[i];
        float xs[4] = {x.x, x.y, x.z, x.w};
        int   es[4] = {e.x, e.y, e.z, e.w};
        int   ts[4] = {t.x, t.y, t.z, t.w};
#pragma unroll
        for (int k = 0; k < 4; k++) {
            unsigned int v = (unsigned int)ts[k] & 0xFFFFu;
            atomicAdd(&S[v], expf(xs[k]));
            if (es[k]) {
                atomicAdd(&m[v], 1u);
                ev_x += xs[k];
                ev_c += 1u;
            }
        }
    }
    // tail (N not divisible by 4) — handled by first few threads
    if (i < tail_cnt) {
        int idx = tail_base + i;
        float xv = x_s[idx];
        unsigned int v = (unsigned int)t_s[idx] & 0xFFFFu;
        atomicAdd(&S[v], expf(xv));
        if (e_s[idx]) {
            atomicAdd(&m[v], 1u);
            ev_x += xv;
            ev_c += 1u;
        }
    }
    // wave-level reduction, one atomic per wave
#pragma unroll
    for (int off = 32; off > 0; off >>= 1) {
        ev_x += __shfl_down(ev_x, off, 64);
        ev_c += __shfl_down(ev_c, off, 64);
    }
    if ((threadIdx.x & 63) == 0) {
        atomicAdd(sum_ex, ev_x);
        atomicAdd(n_ev, ev_c);
    }
}

__global__ __launch_bounds__(256) void finalize_kernel(
        const float* __restrict__ S, const unsigned int* __restrict__ m,
        const float* __restrict__ sum_ex, const unsigned int* __restrict__ n_ev,
        float* __restrict__ out) {
    __shared__ double chunk[256];
    __shared__ double red[256];
    const int t = threadIdx.x;
    const int base = t * (NBUCKETS / 256);   // 256 buckets per thread
    const int CH = NBUCKETS / 256;

    // phase A: per-chunk totals
    double tot = 0.0;
    for (int j = 0; j < CH; j++) tot += (double)S[base + j];
    chunk[t] = tot;
    __syncthreads();

    // exclusive suffix offset for this chunk (sum of all higher chunks)
    double off = 0.0;
    for (int u = t + 1; u < 256; u++) off += chunk[u];

    // phase B: walk chunk from high v to low v, running suffix sum
    double local = 0.0;
    double run = off;
    for (int j = CH - 1; j >= 0; j--) {
        run += (double)S[base + j];
        unsigned int mv = m[base + j];
        if (mv) {
            float denom = (float)run + (float)EPS;
            local += (double)mv * (double)logf(denom);
        }
    }
    red[t] = local;
    __syncthreads();

    for (int s = 128; s > 0; s >>= 1) {
        if (t < s) red[t] += red[t + s];
        __syncthreads();
    }
    if (t == 0) {
        double total = red[0] - (double)(*sum_ex);
        out[0] = (float)(total / ((double)(*n_ev) + EPS));
    }
}

extern "C" void kernel_launch(void* const* d_in, const int* in_sizes, int n_in,
                              void* d_out, int out_size, void* d_ws, size_t ws_size,
                              hipStream_t stream) {
    const float* logits = (const float*)d_in[0];
    const int* status = (const int*)d_in[1];
    const int* time = (const int*)d_in[2];
    const int N = in_sizes[0];

    char* ws = (char*)d_ws;
    float* S = (float*)ws;                                   // 256 KB
    unsigned int* m = (unsigned int*)(ws + NBUCKETS * 4);    // 256 KB
    float* sum_ex = (float*)(ws + NBUCKETS * 8);
    unsigned int* n_ev = (unsigned int*)(ws + NBUCKETS * 8 + 4);

    // 1) zero workspace (it is poisoned before every call)
    zero_ws_kernel<<<(NBUCKETS + 255) / 256, 256, 0, stream>>>(S, m, sum_ex, n_ev);

    // 2) scatter exp(x) and event counts into time buckets
    int n4 = N / 4;
    int tail_base = n4 * 4;
    int tail_cnt = N - tail_base;
    int blocks = (n4 + 255) / 256;
    if (blocks < 1) blocks = 1;
    scatter_kernel<<<blocks, 256, 0, stream>>>(
        (const float4*)logits, (const int4*)status, (const int4*)time,
        S, m, sum_ex, n_ev, n4, logits, status, time, tail_base, tail_cnt);

    // 3) suffix-scan buckets + weighted log-sum + final division
    finalize_kernel<<<1, 256, 0, stream>>>(S, m, sum_ex, n_ev, (float*)d_out);
}

// Round 3
// 479.106 us; speedup vs baseline: 2.3739x; 2.3739x over previous
//
#include <hip/hip_runtime.h>
#include <math.h>

#define NBUCKETS 65536
#define NREP 8
#define EPS 1e-12
#define SCALE_F 1073741824.0f            // 2^30
#define INV_SCALE (1.0 / 1073741824.0)   // 2^-30
#define LOW48 ((1ull << 48) - 1)

typedef float v4f __attribute__((ext_vector_type(4)));
typedef int v4i __attribute__((ext_vector_type(4)));

// ws layout (all 16B-aligned):
//   rep:         NREP * NBUCKETS * u64  = 4 MB     packed per-XCD histograms
//   Sd:          NBUCKETS * double      = 512 KB   reduced exp-sum per bucket
//   m:           NBUCKETS * u32         = 256 KB   event count per bucket
//   chunk_sum:   256 * double           = 2 KB     per-256-bucket-chunk S totals
//   nll_part:    256 * double           = 2 KB     per-chunk m*log(denom) partials
//   nev_part:    256 * u32              = 1 KB     per-chunk event counts
//   sum_ex_part: 8192 * float           = 32 KB    per-scatter-block sum of x over events

#define OFF_REP 0
#define OFF_SD (NREP * NBUCKETS * 8)                       // 4194304
#define OFF_M (OFF_SD + NBUCKETS * 8)                      // 4718592
#define OFF_CS (OFF_M + NBUCKETS * 4)                      // 4980736
#define OFF_NLL (OFF_CS + 256 * 8)                         // 4982784
#define OFF_NEV (OFF_NLL + 256 * 8)                        // 4984832
#define OFF_SX (OFF_NEV + 256 * 4)                         // 4985856

__device__ __forceinline__ unsigned int xcd_id() {
    unsigned int x;
    asm volatile("s_getreg_b32 %0, hwreg(HW_REG_XCC_ID)" : "=s"(x));
    return x & 7u;
}

__global__ void zero_ws_kernel(unsigned long long* __restrict__ rep, int n) {
    int i = blockIdx.x * blockDim.x + threadIdx.x;
    if (i < n) rep[i] = 0ull;
}

__global__ __launch_bounds__(256) void scatter_kernel(
        const v4f* __restrict__ x4, const v4i* __restrict__ e4,
        const v4i* __restrict__ t4,
        unsigned long long* __restrict__ rep, float* __restrict__ sum_ex_part,
        int n4, const float* __restrict__ x_s, const int* __restrict__ e_s,
        const int* __restrict__ t_s, int tail_base, int tail_cnt) {
    int i = blockIdx.x * blockDim.x + threadIdx.x;
    unsigned long long* R = rep + (size_t)xcd_id() * NBUCKETS;
    float ev_x = 0.0f;

    if (i < n4) {
        v4f x = __builtin_nontemporal_load(&x4[i]);
        v4i e = __builtin_nontemporal_load(&e4[i]);
        v4i t = __builtin_nontemporal_load(&t4[i]);
#pragma unroll
        for (int k = 0; k < 4; k++) {
            float xv = x[k];
            unsigned int v = (unsigned int)t[k] & 0xFFFFu;
            float ex = expf(xv);
            unsigned long long pk =
                ((unsigned long long)(e[k] != 0) << 48) +
                (unsigned long long)(ex * SCALE_F + 0.5f);
            __hip_atomic_fetch_add(&R[v], pk, __ATOMIC_RELAXED,
                                   __HIP_MEMORY_SCOPE_WORKGROUP);
            if (e[k]) ev_x += xv;
        }
    }
    if (i < tail_cnt) {
        int idx = tail_base + i;
        float xv = x_s[idx];
        unsigned int v = (unsigned int)t_s[idx] & 0xFFFFu;
        unsigned long long pk =
            ((unsigned long long)(e_s[idx] != 0) << 48) +
            (unsigned long long)(expf(xv) * SCALE_F + 0.5f);
        __hip_atomic_fetch_add(&R[v], pk, __ATOMIC_RELAXED,
                               __HIP_MEMORY_SCOPE_WORKGROUP);
        if (e_s[idx]) ev_x += xv;
    }

    // block reduce ev_x -> one non-atomic partial per block
    __shared__ float sred[256];
    sred[threadIdx.x] = ev_x;
    __syncthreads();
    for (int s = 128; s > 0; s >>= 1) {
        if ((int)threadIdx.x < s) sred[threadIdx.x] += sred[threadIdx.x + s];
        __syncthreads();
    }
    if (threadIdx.x == 0) sum_ex_part[blockIdx.x] = sred[0];
}

// 256 blocks x 256 threads: sum replicas, unpack, emit per-chunk totals.
__global__ __launch_bounds__(256) void reduce_kernel(
        const unsigned long long* __restrict__ rep, double* __restrict__ Sd,
        unsigned int* __restrict__ m, double* __restrict__ chunk_sum) {
    int t = threadIdx.x;
    int i = blockIdx.x * 256 + t;
    unsigned long long acc = 0ull;
#pragma unroll
    for (int r = 0; r < NREP; r++) acc += rep[(size_t)r * NBUCKETS + i];
    double sv = (double)(acc & LOW48) * INV_SCALE;
    unsigned int mv = (unsigned int)(acc >> 48);
    Sd[i] = sv;
    m[i] = mv;
    __shared__ double red[256];
    red[t] = sv;
    __syncthreads();
    for (int s = 128; s > 0; s >>= 1) {
        if (t < s) red[t] += red[t + s];
        __syncthreads();
    }
    if (t == 0) chunk_sum[blockIdx.x] = red[0];
}

// 256 blocks x 256 threads: block b handles buckets [b*256, b*256+256).
// Suffix-sum within chunk + cross-chunk offset; accumulate m*log(denom).
__global__ __launch_bounds__(256) void suffix_kernel(
        const double* __restrict__ Sd, const unsigned int* __restrict__ m,
        const double* __restrict__ chunk_sum, double* __restrict__ nll_part,
        unsigned int* __restrict__ nev_part) {
    __shared__ double cs[256];
    __shared__ double sfx[256];
    __shared__ unsigned int ured[256];
    const int t = threadIdx.x;
    const int b = blockIdx.x;

    // offset = sum of chunk_sum[c] for all chunks c > b (higher buckets = larger time)
    cs[t] = (t > b) ? chunk_sum[t] : 0.0;
    __syncthreads();
    for (int s = 128; s > 0; s >>= 1) {
        if (t < s) cs[t] += cs[t + s];
        __syncthreads();
    }
    double offset = cs[0];
    __syncthreads();

    int i = b * 256 + t;
    double sv = Sd[i];
    unsigned int mv = m[i];

    // inclusive suffix scan within chunk: sfx[t] = sum_{j>=t} sv_j
    sfx[t] = sv;
    __syncthreads();
    for (int s = 1; s < 256; s <<= 1) {
        double add = (t + s < 256) ? sfx[t + s] : 0.0;
        __syncthreads();
        sfx[t] += add;
        __syncthreads();
    }

    double denom = offset + sfx[t] + EPS;
    double nll = (mv != 0u) ? (double)mv * log(denom) : 0.0;

    // block reduce nll and event count
    cs[t] = nll;
    ured[t] = mv;
    __syncthreads();
    for (int s = 128; s > 0; s >>= 1) {
        if (t < s) { cs[t] += cs[t + s]; ured[t] += ured[t + s]; }
        __syncthreads();
    }
    if (t == 0) {
        nll_part[b] = cs[0];
        nev_part[b] = ured[0];
    }
}

__global__ __launch_bounds__(256) void final_kernel(
        const double* __restrict__ nll_part, const unsigned int* __restrict__ nev_part,
        const float* __restrict__ sum_ex_part, int n_sx, float* __restrict__ out) {
    __shared__ double rd[256];
    __shared__ double rs[256];
    __shared__ unsigned int ru[256];
    int t = threadIdx.x;
    double nll = nll_part[t];
    unsigned int ne = nev_part[t];
    double sx = 0.0;
    for (int i = t; i < n_sx; i += 256) sx += (double)sum_ex_part[i];
    rd[t] = nll;
    rs[t] = sx;
    ru[t] = ne;
    __syncthreads();
    for (int s = 128; s > 0; s >>= 1) {
        if (t < s) { rd[t] += rd[t + s]; rs[t] += rs[t + s]; ru[t] += ru[t + s]; }
        __syncthreads();
    }
    if (t == 0) {
        double total = rd[0] - rs[0];
        out[0] = (float)(total / ((double)ru[0] + EPS));
    }
}

extern "C" void kernel_launch(void* const* d_in, const int* in_sizes, int n_in,
                              void* d_out, int out_size, void* d_ws, size_t ws_size,
                              hipStream_t stream) {
    const float* logits = (const float*)d_in[0];
    const int* status = (const int*)d_in[1];
    const int* time = (const int*)d_in[2];
    const int N = in_sizes[0];

    char* ws = (char*)d_ws;
    unsigned long long* rep = (unsigned long long*)(ws + OFF_REP);
    double* Sd = (double*)(ws + OFF_SD);
    unsigned int* m = (unsigned int*)(ws + OFF_M);
    double* chunk_sum = (double*)(ws + OFF_CS);
    double* nll_part = (double*)(ws + OFF_NLL);
    unsigned int* nev_part = (unsigned int*)(ws + OFF_NEV);
    float* sum_ex_part = (float*)(ws + OFF_SX);

    // 1) zero the replica histograms (ws is poisoned before every call)
    int nrep_total = NREP * NBUCKETS;
    zero_ws_kernel<<<(nrep_total + 255) / 256, 256, 0, stream>>>(rep, nrep_total);

    // 2) scatter packed (exp<<0 | event<<48) into the XCD-local replica
    int n4 = N / 4;
    int tail_base = n4 * 4;
    int tail_cnt = N - tail_base;
    int blocks = (n4 + 255) / 256;
    if (blocks < 1) blocks = 1;
    scatter_kernel<<<blocks, 256, 0, stream>>>(
        (const v4f*)logits, (const v4i*)status, (const v4i*)time,
        rep, sum_ex_part, n4, logits, status, time, tail_base, tail_cnt);

    // 3) sum replicas -> per-bucket S (double) + m, and per-chunk totals
    reduce_kernel<<<256, 256, 0, stream>>>(rep, Sd, m, chunk_sum);

    // 4) suffix scan + m*log(denom) per chunk
    suffix_kernel<<<256, 256, 0, stream>>>(Sd, m, chunk_sum, nll_part, nev_part);

    // 5) final combine
    final_kernel<<<1, 256, 0, stream>>>(nll_part, nev_part, sum_ex_part, blocks,
                                        (float*)d_out);
}

// Round 4
// 171.187 us; speedup vs baseline: 6.6440x; 2.7987x over previous
//
#include <hip/hip_runtime.h>
#include <math.h>

#define NBUCKETS 65536
#define EPS 1e-12

typedef float v4f __attribute__((ext_vector_type(4)));
typedef int v4i __attribute__((ext_vector_type(4)));
typedef unsigned int v4u __attribute__((ext_vector_type(4)));

// ---------------- new path (LDS histogram, no global atomics) ----------------
#define NWG 256
#define WGT 1024
#define RROUNDS 8           // v4 loads per thread -> 32 items/thread
#define PASSES 4
#define PBUCK 16384         // buckets per pass (64 KB LDS)
#define SCALE_F 131072.0f   // 2^17 fixed point
#define INV_SCALE (1.0 / 131072.0)
#define SUM_MASK 0x0FFFFFFFu

// new ws layout
#define OFF_HIST 0                                         // 256*65536*4 = 64 MB
#define OFF_SD   (NWG * NBUCKETS * 4)                      // 67108864
#define OFF_M    (OFF_SD + NBUCKETS * 8)                   // 67633152
#define OFF_CS   (OFF_M + NBUCKETS * 4)                    // 67895296
#define OFF_NLL  (OFF_CS + 256 * 8)                        // 67897344
#define OFF_NEV  (OFF_NLL + 256 * 8)                       // 67899392
#define OFF_SX   (OFF_NEV + 256 * 4)                       // 67900416
#define REQ_NEW  (OFF_SX + NWG * 4)                        // ~64.8 MB

// old (fallback) ws layout
#define NREP 8
#define OSCALE_F 1073741824.0f
#define OINV_SCALE (1.0 / 1073741824.0)
#define LOW48 ((1ull << 48) - 1)
#define O_REP 0
#define O_SD (NREP * NBUCKETS * 8)
#define O_M (O_SD + NBUCKETS * 8)
#define O_CS (O_M + NBUCKETS * 4)
#define O_NLL (O_CS + 256 * 8)
#define O_NEV (O_NLL + 256 * 8)
#define O_SX (O_NEV + 256 * 4)
#define REQ_OLD (O_SX + 8192 * 4)

__device__ __forceinline__ unsigned int xcd_id() {
    unsigned int x;
    asm volatile("s_getreg_b32 %0, hwreg(HW_REG_XCC_ID)" : "=s"(x));
    return x & 7u;
}

// ------------------------- new scatter: registers -> LDS -> hist -------------------------
__global__ __launch_bounds__(WGT, 4) void scatter_lds_kernel(
        const v4f* __restrict__ x4, const v4i* __restrict__ e4,
        const v4i* __restrict__ t4, unsigned int* __restrict__ hist,
        float* __restrict__ sum_ex_part, int n4,
        const float* __restrict__ x_s, const int* __restrict__ e_s,
        const int* __restrict__ t_s, int tail_base, int tail_cnt) {
    __shared__ unsigned int lds[PBUCK];
    const int t = threadIdx.x;
    const int wg = blockIdx.x;

    unsigned int pk[RROUNDS * 4];
    unsigned int bk[RROUNDS * 4];
    float ev_x = 0.0f;

#pragma unroll
    for (int r = 0; r < RROUNDS; r++) {
        int idx = (wg * RROUNDS + r) * WGT + t;
        bool ok = idx < n4;
        v4f x = {0.0f, 0.0f, 0.0f, 0.0f};
        v4i e = {0, 0, 0, 0};
        v4i tm = {0, 0, 0, 0};
        if (ok) {
            x = __builtin_nontemporal_load(&x4[idx]);
            e = __builtin_nontemporal_load(&e4[idx]);
            tm = __builtin_nontemporal_load(&t4[idx]);
        }
#pragma unroll
        for (int k = 0; k < 4; k++) {
            int j = r * 4 + k;
            if (ok) {
                float xv = x[k];
                unsigned int ev = (e[k] != 0) ? 1u : 0u;
                pk[j] = (ev << 28) + (unsigned int)(expf(xv) * SCALE_F + 0.5f);
                bk[j] = (unsigned int)tm[k] & 0xFFFFu;
                if (ev) ev_x += xv;
            } else {
                pk[j] = 0u;
                bk[j] = 0u;
            }
        }
    }

    // N%4 tail: wg 0 / thread 0 stashes up to 3 scalar items
    unsigned int pkt[4], bkt[4];
    int my_tail = 0;
    if (wg == 0 && t == 0 && tail_cnt > 0) {
        my_tail = tail_cnt;
        for (int i = 0; i < tail_cnt; i++) {
            int idx = tail_base + i;
            float xv = x_s[idx];
            unsigned int ev = (e_s[idx] != 0) ? 1u : 0u;
            pkt[i] = (ev << 28) + (unsigned int)(expf(xv) * SCALE_F + 0.5f);
            bkt[i] = (unsigned int)t_s[idx] & 0xFFFFu;
            if (ev) ev_x += xv;
        }
    }

    v4u* lds4 = (v4u*)lds;
#pragma unroll 1
    for (int p = 0; p < PASSES; p++) {
#pragma unroll
        for (int q = 0; q < PBUCK / 4 / WGT; q++)
            lds4[t + q * WGT] = (v4u){0u, 0u, 0u, 0u};
        __syncthreads();

        unsigned int up = (unsigned int)p;
#pragma unroll
        for (int j = 0; j < RROUNDS * 4; j++) {
            if (pk[j] != 0u && (bk[j] >> 14) == up)
                atomicAdd(&lds[bk[j] & (PBUCK - 1)], pk[j]);
        }
        for (int i = 0; i < my_tail; i++) {
            if ((bkt[i] >> 14) == up)
                atomicAdd(&lds[bkt[i] & (PBUCK - 1)], pkt[i]);
        }
        __syncthreads();

        // coalesced write-out of this pass's 16K-bucket slab
        v4u* hbase = (v4u*)(hist + (size_t)wg * NBUCKETS + (size_t)p * PBUCK);
#pragma unroll
        for (int q = 0; q < PBUCK / 4 / WGT; q++) {
            v4u v = lds4[t + q * WGT];
            __builtin_nontemporal_store(v, &hbase[t + q * WGT]);
        }
        __syncthreads();
    }

    // wave-reduce ev_x, then cross-wave via LDS (reuse lds, barriered above)
#pragma unroll
    for (int off = 32; off > 0; off >>= 1) ev_x += __shfl_down(ev_x, off, 64);
    if ((t & 63) == 0) lds[t >> 6] = __float_as_uint(ev_x);
    __syncthreads();
    if (t == 0) {
        float s = 0.0f;
        for (int w = 0; w < WGT / 64; w++) s += __uint_as_float(lds[w]);
        sum_ex_part[wg] = s;
    }
}

// merge 256 per-wg histograms -> Sd, m, chunk_sum. block b = buckets [b*256, b*256+256)
__global__ __launch_bounds__(256) void merge_chunk_kernel(
        const unsigned int* __restrict__ hist, double* __restrict__ Sd,
        unsigned int* __restrict__ m, double* __restrict__ chunk_sum) {
    int t = threadIdx.x, b = blockIdx.x;
    int i = b * 256 + t;
    unsigned long long s = 0ull;
    unsigned int c = 0u;
#pragma unroll 4
    for (int wg = 0; wg < NWG; wg++) {
        unsigned int h = hist[(size_t)wg * NBUCKETS + i];
        s += (unsigned long long)(h & SUM_MASK);
        c += (h >> 28);
    }
    double sv = (double)s * INV_SCALE;
    Sd[i] = sv;
    m[i] = c;
    __shared__ double red[256];
    red[t] = sv;
    __syncthreads();
    for (int st = 128; st > 0; st >>= 1) {
        if (t < st) red[t] += red[t + st];
        __syncthreads();
    }
    if (t == 0) chunk_sum[b] = red[0];
}

// ------------------------- old (fallback) path kernels -------------------------
__global__ void zero_ws_kernel(unsigned long long* __restrict__ rep, int n) {
    int i = blockIdx.x * blockDim.x + threadIdx.x;
    if (i < n) rep[i] = 0ull;
}

__global__ __launch_bounds__(256) void scatter_atomic_kernel(
        const v4f* __restrict__ x4, const v4i* __restrict__ e4,
        const v4i* __restrict__ t4,
        unsigned long long* __restrict__ rep, float* __restrict__ sum_ex_part,
        int n4, const float* __restrict__ x_s, const int* __restrict__ e_s,
        const int* __restrict__ t_s, int tail_base, int tail_cnt) {
    int i = blockIdx.x * blockDim.x + threadIdx.x;
    unsigned long long* R = rep + (size_t)xcd_id() * NBUCKETS;
    float ev_x = 0.0f;
    if (i < n4) {
        v4f x = __builtin_nontemporal_load(&x4[i]);
        v4i e = __builtin_nontemporal_load(&e4[i]);
        v4i t = __builtin_nontemporal_load(&t4[i]);
#pragma unroll
        for (int k = 0; k < 4; k++) {
            float xv = x[k];
            unsigned int v = (unsigned int)t[k] & 0xFFFFu;
            unsigned long long pk =
                ((unsigned long long)(e[k] != 0) << 48) +
                (unsigned long long)(expf(xv) * OSCALE_F + 0.5f);
            __hip_atomic_fetch_add(&R[v], pk, __ATOMIC_RELAXED,
                                   __HIP_MEMORY_SCOPE_WORKGROUP);
            if (e[k]) ev_x += xv;
        }
    }
    if (i < tail_cnt) {
        int idx = tail_base + i;
        float xv = x_s[idx];
        unsigned int v = (unsigned int)t_s[idx] & 0xFFFFu;
        unsigned long long pk =
            ((unsigned long long)(e_s[idx] != 0) << 48) +
            (unsigned long long)(expf(xv) * OSCALE_F + 0.5f);
        __hip_atomic_fetch_add(&R[v], pk, __ATOMIC_RELAXED,
                               __HIP_MEMORY_SCOPE_WORKGROUP);
        if (e_s[idx]) ev_x += xv;
    }
    __shared__ float sred[256];
    sred[threadIdx.x] = ev_x;
    __syncthreads();
    for (int s = 128; s > 0; s >>= 1) {
        if ((int)threadIdx.x < s) sred[threadIdx.x] += sred[threadIdx.x + s];
        __syncthreads();
    }
    if (threadIdx.x == 0) sum_ex_part[blockIdx.x] = sred[0];
}

__global__ __launch_bounds__(256) void reduce_kernel(
        const unsigned long long* __restrict__ rep, double* __restrict__ Sd,
        unsigned int* __restrict__ m, double* __restrict__ chunk_sum) {
    int t = threadIdx.x;
    int i = blockIdx.x * 256 + t;
    unsigned long long acc = 0ull;
#pragma unroll
    for (int r = 0; r < NREP; r++) acc += rep[(size_t)r * NBUCKETS + i];
    double sv = (double)(acc & LOW48) * OINV_SCALE;
    unsigned int mv = (unsigned int)(acc >> 48);
    Sd[i] = sv;
    m[i] = mv;
    __shared__ double red[256];
    red[t] = sv;
    __syncthreads();
    for (int s = 128; s > 0; s >>= 1) {
        if (t < s) red[t] += red[t + s];
        __syncthreads();
    }
    if (t == 0) chunk_sum[blockIdx.x] = red[0];
}

// ------------------------- shared tail kernels -------------------------
__global__ __launch_bounds__(256) void suffix_kernel(
        const double* __restrict__ Sd, const unsigned int* __restrict__ m,
        const double* __restrict__ chunk_sum, double* __restrict__ nll_part,
        unsigned int* __restrict__ nev_part) {
    __shared__ double cs[256];
    __shared__ double sfx[256];
    __shared__ unsigned int ured[256];
    const int t = threadIdx.x;
    const int b = blockIdx.x;

    cs[t] = (t > b) ? chunk_sum[t] : 0.0;
    __syncthreads();
    for (int s = 128; s > 0; s >>= 1) {
        if (t < s) cs[t] += cs[t + s];
        __syncthreads();
    }
    double offset = cs[0];
    __syncthreads();

    int i = b * 256 + t;
    double sv = Sd[i];
    unsigned int mv = m[i];

    sfx[t] = sv;
    __syncthreads();
    for (int s = 1; s < 256; s <<= 1) {
        double add = (t + s < 256) ? sfx[t + s] : 0.0;
        __syncthreads();
        sfx[t] += add;
        __syncthreads();
    }

    double denom = offset + sfx[t] + EPS;
    double nll = (mv != 0u) ? (double)mv * log(denom) : 0.0;

    cs[t] = nll;
    ured[t] = mv;
    __syncthreads();
    for (int s = 128; s > 0; s >>= 1) {
        if (t < s) { cs[t] += cs[t + s]; ured[t] += ured[t + s]; }
        __syncthreads();
    }
    if (t == 0) {
        nll_part[b] = cs[0];
        nev_part[b] = ured[0];
    }
}

__global__ __launch_bounds__(256) void final_kernel(
        const double* __restrict__ nll_part, const unsigned int* __restrict__ nev_part,
        const float* __restrict__ sum_ex_part, int n_sx, float* __restrict__ out) {
    __shared__ double rd[256];
    __shared__ double rs[256];
    __shared__ unsigned int ru[256];
    int t = threadIdx.x;
    double nll = nll_part[t];
    unsigned int ne = nev_part[t];
    double sx = 0.0;
    for (int i = t; i < n_sx; i += 256) sx += (double)sum_ex_part[i];
    rd[t] = nll;
    rs[t] = sx;
    ru[t] = ne;
    __syncthreads();
    for (int s = 128; s > 0; s >>= 1) {
        if (t < s) { rd[t] += rd[t + s]; rs[t] += rs[t + s]; ru[t] += ru[t + s]; }
        __syncthreads();
    }
    if (t == 0) {
        double total = rd[0] - rs[0];
        out[0] = (float)(total / ((double)ru[0] + EPS));
    }
}

extern "C" void kernel_launch(void* const* d_in, const int* in_sizes, int n_in,
                              void* d_out, int out_size, void* d_ws, size_t ws_size,
                              hipStream_t stream) {
    const float* logits = (const float*)d_in[0];
    const int* status = (const int*)d_in[1];
    const int* time = (const int*)d_in[2];
    const int N = in_sizes[0];

    char* ws = (char*)d_ws;
    int n4 = N / 4;
    int tail_base = n4 * 4;
    int tail_cnt = N - tail_base;

    if (ws_size >= (size_t)REQ_NEW && N <= NWG * WGT * RROUNDS * 4) {
        unsigned int* hist = (unsigned int*)(ws + OFF_HIST);
        double* Sd = (double*)(ws + OFF_SD);
        unsigned int* m = (unsigned int*)(ws + OFF_M);
        double* chunk_sum = (double*)(ws + OFF_CS);
        double* nll_part = (double*)(ws + OFF_NLL);
        unsigned int* nev_part = (unsigned int*)(ws + OFF_NEV);
        float* sum_ex_part = (float*)(ws + OFF_SX);

        scatter_lds_kernel<<<NWG, WGT, 0, stream>>>(
            (const v4f*)logits, (const v4i*)status, (const v4i*)time,
            hist, sum_ex_part, n4, logits, status, time, tail_base, tail_cnt);
        merge_chunk_kernel<<<256, 256, 0, stream>>>(hist, Sd, m, chunk_sum);
        suffix_kernel<<<256, 256, 0, stream>>>(Sd, m, chunk_sum, nll_part, nev_part);
        final_kernel<<<1, 256, 0, stream>>>(nll_part, nev_part, sum_ex_part, NWG,
                                            (float*)d_out);
    } else {
        unsigned long long* rep = (unsigned long long*)(ws + O_REP);
        double* Sd = (double*)(ws + O_SD);
        unsigned int* m = (unsigned int*)(ws + O_M);
        double* chunk_sum = (double*)(ws + O_CS);
        double* nll_part = (double*)(ws + O_NLL);
        unsigned int* nev_part = (unsigned int*)(ws + O_NEV);
        float* sum_ex_part = (float*)(ws + O_SX);

        int nrep_total = NREP * NBUCKETS;
        zero_ws_kernel<<<(nrep_total + 255) / 256, 256, 0, stream>>>(rep, nrep_total);
        int blocks = (n4 + 255) / 256;
        if (blocks < 1) blocks = 1;
        scatter_atomic_kernel<<<blocks, 256, 0, stream>>>(
            (const v4f*)logits, (const v4i*)status, (const v4i*)time,
            rep, sum_ex_part, n4, logits, status, time, tail_base, tail_cnt);
        reduce_kernel<<<256, 256, 0, stream>>>(rep, Sd, m, chunk_sum);
        suffix_kernel<<<256, 256, 0, stream>>>(Sd, m, chunk_sum, nll_part, nev_part);
        final_kernel<<<1, 256, 0, stream>>>(nll_part, nev_part, sum_ex_part, blocks,
                                            (float*)d_out);
    }
}